// Round 4
// baseline (111.956 us; speedup 1.0000x reference)
//
#include <hip/hip_runtime.h>

// GNN layer: deg-normalized aggregation -> Linear+ReLU -> LayerNorm
// N=10000, E=640000, D=128. CSR-by-dest with ZERO global atomics.
// Pipeline: hist (per-block LDS histograms + per-edge ranks) -> colscan
// (block prefixes + dinv) -> scan (offsets) -> fillscale (CSR fill + H*dinv
// pre-scale, fused) -> agg (pure gather-add) -> mmln (matmul+ReLU+LN).

#define DFEAT 128
#define MAXN 10240   // compile-time bin capacity (N=10000)

// Packed per-block histogram in LDS: low16 = out-degree(row), high16 = in-degree(col).
// Per-block edge count Epb <= 40000 (nblk>=16) so halves never carry.
// Records each edge's within-(block,bin) rank for the dest histogram.
__global__ __launch_bounds__(1024) void hist_kernel(
    const int* __restrict__ ei, int E, int Epb, int N,
    int* __restrict__ packedHist, unsigned short* __restrict__ rank16) {
    __shared__ unsigned int h[MAXN];
    int t = threadIdx.x;
    int b = blockIdx.x;
    for (int i = t; i < N; i += 1024) h[i] = 0u;
    __syncthreads();
    int e0 = b * Epb, e1 = min(E, e0 + Epb);
    for (int e = e0 + t; e < e1; e += 1024) {
        atomicAdd(&h[ei[e]], 1u);                               // source -> low16
        unsigned int old = atomicAdd(&h[ei[E + e]], 0x10000u);  // dest -> high16
        rank16[e] = (unsigned short)(old >> 16);
    }
    __syncthreads();
    for (int i = t; i < N; i += 1024) packedHist[b * N + i] = (int)h[i];
}

// Per-bin: sum row counts -> dinv; exclusive-prefix col counts across blocks
// IN PLACE (packedHist -> blkpref) and total -> tot. k*N+b coalesced.
__global__ __launch_bounds__(64) void colscan_kernel(
    int* __restrict__ packedHist, float* __restrict__ dinv,
    int* __restrict__ tot, int N, int nblk) {
    int b = blockIdx.x * 64 + threadIdx.x;
    if (b >= N) return;
    int sR = 0, sC = 0;
#pragma unroll 8
    for (int k = 0; k < nblk; ++k) {
        unsigned int v = (unsigned int)packedHist[k * N + b];
        sR += (int)(v & 0xffffu);
        packedHist[k * N + b] = sC;
        sC += (int)(v >> 16);
    }
    dinv[b] = 1.0f / (float)(sR + 1);  // +1 self-loop; always >= 1
    tot[b] = sC;
}

// Single-block exclusive scan, 2 barriers: thread-local serial chunk +
// shfl wave scan + wave0 scan of wave sums. Requires B <= 24.
__global__ __launch_bounds__(1024) void scan_kernel(const int* __restrict__ cnt,
                                                    int* __restrict__ offs, int N, int B) {
    __shared__ int wsum[16];
    int t = threadIdx.x;
    int lane = t & 63, wv = t >> 6;
    int v[24];
    int base = t * B;
    int s = 0;
#pragma unroll
    for (int j = 0; j < 24; ++j) {
        if (j < B) {
            int idx = base + j;
            int x = (idx < N) ? cnt[idx] : 0;
            v[j] = s;  // thread-local exclusive prefix
            s += x;
        }
    }
    int inc = s;  // wave-inclusive scan of per-thread sums
    for (int o = 1; o < 64; o <<= 1) {
        int u = __shfl_up(inc, o);
        if (lane >= o) inc += u;
    }
    if (lane == 63) wsum[wv] = inc;
    __syncthreads();
    if (wv == 0 && lane < 16) {
        int ws = wsum[lane];
        for (int o = 1; o < 16; o <<= 1) {
            int u = __shfl_up(ws, o);
            if (lane >= o) ws += u;
        }
        wsum[lane] = ws;  // inclusive wave prefix
    }
    __syncthreads();
    int wpre = (wv == 0) ? 0 : wsum[wv - 1];
    int tpre = wpre + inc - s;  // exclusive prefix for this thread's chunk
#pragma unroll
    for (int j = 0; j < 24; ++j) {
        if (j < B) {
            int idx = base + j;
            if (idx < N) offs[idx] = tpre + v[j];
        }
    }
    if (t == 1023) offs[N] = wpre + inc;
}

// Fused: (A) Hs = H * dinv[node] pre-scale, grid-stride; (B) stateless CSR
// fill, hist-block-aligned (no division, no LDS, no atomics).
__global__ __launch_bounds__(256) void fillscale_kernel(
    const int* __restrict__ ei, int E, int Epb, int N,
    const int* __restrict__ offs, const int* __restrict__ blkpref,
    const unsigned short* __restrict__ rank16, unsigned short* __restrict__ edge_src,
    const float* __restrict__ H, const float* __restrict__ dinv,
    float* __restrict__ Hs, int nblk, int subPerBlk) {
    // phase A: pre-scale
    {
        int tid = blockIdx.x * 256 + threadIdx.x;
        int total = N * 64;
        int stride = gridDim.x * 256;
        const float2* __restrict__ H2 = (const float2*)H;
        float2* __restrict__ Hs2 = (float2*)Hs;
        for (int i = tid; i < total; i += stride) {
            float d = dinv[i >> 6];
            float2 h = H2[i];
            h.x *= d;
            h.y *= d;
            Hs2[i] = h;
        }
    }
    // phase B: fill (block-uniform hist-block id)
    int b = blockIdx.x / subPerBlk;
    int sub = blockIdx.x - b * subPerBlk;
    if (b < nblk) {
        int e0 = b * Epb, e1 = min(E, e0 + Epb);
        const int* __restrict__ pre = blkpref + b * N;
        int stride = subPerBlk * 256;
        for (int e = e0 + sub * 256 + threadIdx.x; e < e1; e += stride) {
            int c = ei[E + e];
            edge_src[offs[c] + pre[c] + (int)rank16[e]] = (unsigned short)ei[e];
        }
    }
}

// One wave per destination node (4 nodes / 256-thread block); lane holds
// float2. Pure adds: Hs is pre-scaled, self message is Hs[c].
__global__ __launch_bounds__(256) void agg_kernel(
    const float* __restrict__ Hs, const int* __restrict__ offs,
    const unsigned short* __restrict__ edge_src, float* __restrict__ Hagg, int N) {
    int wave = threadIdx.x >> 6, t = threadIdx.x & 63;
    int c = blockIdx.x * 4 + wave;
    if (c >= N) return;
    const float2* __restrict__ Hs2 = (const float2*)Hs;
    float2 self = Hs2[c * 64 + t];
    float ax = self.x, ay = self.y;
    int e = offs[c], end = offs[c + 1];
    for (; e + 8 <= end; e += 8) {
        int s0 = edge_src[e], s1 = edge_src[e + 1], s2 = edge_src[e + 2], s3 = edge_src[e + 3];
        int s4 = edge_src[e + 4], s5 = edge_src[e + 5], s6 = edge_src[e + 6], s7 = edge_src[e + 7];
        float2 h0 = Hs2[s0 * 64 + t], h1 = Hs2[s1 * 64 + t];
        float2 h2 = Hs2[s2 * 64 + t], h3 = Hs2[s3 * 64 + t];
        float2 h4 = Hs2[s4 * 64 + t], h5 = Hs2[s5 * 64 + t];
        float2 h6 = Hs2[s6 * 64 + t], h7 = Hs2[s7 * 64 + t];
        ax += h0.x + h1.x + h2.x + h3.x + h4.x + h5.x + h6.x + h7.x;
        ay += h0.y + h1.y + h2.y + h3.y + h4.y + h5.y + h6.y + h7.y;
    }
    for (; e < end; ++e) {
        float2 h = Hs2[edge_src[e] * 64 + t];
        ax += h.x;
        ay += h.y;
    }
    float2 out;
    out.x = ax;
    out.y = ay;
    ((float2*)Hagg)[c * 64 + t] = out;
}

// Fused: out = LN(relu(Hagg @ W^T + b)) * gamma + beta (in place on HO).
// W in LDS transposed + XOR-swizzled; each wave computes 4 nodes (w reuse x4).
__global__ __launch_bounds__(256) void mmln_kernel(
    const float* __restrict__ W, const float* __restrict__ bias,
    const float* __restrict__ gamma, const float* __restrict__ beta,
    float* __restrict__ HO, int N) {
    __shared__ float Wt[128 * 128];
    int t = threadIdx.x;
    {
        const float4* __restrict__ W4 = (const float4*)W;
        for (int i4 = t; i4 < 128 * 32; i4 += 256) {
            float4 w = W4[i4];
            int i = i4 * 4;
            int d = i >> 7, k0 = i & 127;
            Wt[(k0 + 0) * 128 + (d ^ ((k0 + 0) & 31))] = w.x;
            Wt[(k0 + 1) * 128 + (d ^ ((k0 + 1) & 31))] = w.y;
            Wt[(k0 + 2) * 128 + (d ^ ((k0 + 2) & 31))] = w.z;
            Wt[(k0 + 3) * 128 + (d ^ ((k0 + 3) & 31))] = w.w;
        }
    }
    __syncthreads();

    int wave = t >> 6, lane = t & 63;
    int d0 = lane, d1 = lane + 64;
    float b0 = bias[d0], b1 = bias[d1];
    float g0 = gamma[d0], g1 = gamma[d1];
    float be0 = beta[d0], be1 = beta[d1];

    const int NB = 16;  // nodes per block pass, 4 per wave
    int nbatches = (N + NB - 1) / NB;
    for (int batch = blockIdx.x; batch < nbatches; batch += gridDim.x) {
        int n0 = batch * NB + wave * 4;
        bool has[4];
        const float* r[4];
#pragma unroll
        for (int j = 0; j < 4; ++j) {
            has[j] = (n0 + j) < N;
            r[j] = HO + (size_t)(has[j] ? (n0 + j) : 0) * 128;
        }
        float a[4][2];
#pragma unroll
        for (int j = 0; j < 4; ++j) {
            a[j][0] = b0;
            a[j][1] = b1;
        }
#pragma unroll 4
        for (int k = 0; k < 128; ++k) {
            float w0 = Wt[k * 128 + (d0 ^ (k & 31))];
            float w1 = Wt[k * 128 + (d1 ^ (k & 31))];
#pragma unroll
            for (int j = 0; j < 4; ++j) {
                float x = r[j][k];
                a[j][0] += x * w0;
                a[j][1] += x * w1;
            }
        }
#pragma unroll
        for (int j = 0; j < 4; ++j) {
            float v0 = fmaxf(a[j][0], 0.f), v1 = fmaxf(a[j][1], 0.f);
            float s = v0 + v1, q = v0 * v0 + v1 * v1;
            for (int o = 32; o; o >>= 1) {
                s += __shfl_xor(s, o);
                q += __shfl_xor(q, o);
            }
            float mean = s * (1.0f / 128.0f);
            float var = q * (1.0f / 128.0f) - mean * mean;
            float rstd = rsqrtf(var + 1e-5f);
            if (has[j]) {
                HO[(size_t)(n0 + j) * 128 + d0] = (v0 - mean) * rstd * g0 + be0;
                HO[(size_t)(n0 + j) * 128 + d1] = (v1 - mean) * rstd * g1 + be1;
            }
        }
    }
}

extern "C" void kernel_launch(void* const* d_in, const int* in_sizes, int n_in,
                              void* d_out, int out_size, void* d_ws, size_t ws_size,
                              hipStream_t stream) {
    const float* H = (const float*)d_in[0];
    const int* ei = (const int*)d_in[1];
    const float* W = (const float*)d_in[3];
    const float* bias = (const float*)d_in[4];
    const float* gamma = (const float*)d_in[5];
    const float* beta = (const float*)d_in[6];
    float* out = (float*)d_out;

    const int N = in_sizes[0] / DFEAT;  // 10000 (<= MAXN)
    const int E = in_sizes[1] / 2;      // 640000

    auto align256 = [](size_t x) { return (x + 255) & ~(size_t)255; };
    // largest nblk in {128,64,32} whose workspace fits (Epb <= 40000 -> u16 ranks ok)
    int nblk = 128;
    while (nblk > 32) {
        size_t need = align256((size_t)nblk * N * 4) + align256((size_t)E * 2) * 2 +
                      align256((size_t)N * DFEAT * 4) + align256((size_t)(N + 1) * 4) +
                      align256((size_t)N * 4) * 2;
        if (need <= ws_size || ws_size == 0) break;
        nblk >>= 1;
    }
    const int Epb = (E + nblk - 1) / nblk;

    char* w = (char*)d_ws;
    auto alloc = [&](size_t bytes) {
        char* p = w;
        w += (bytes + 255) & ~(size_t)255;
        return p;
    };
    int* packedHist = (int*)alloc((size_t)nblk * N * 4);  // -> blkpref after colscan
    unsigned short* rank16 = (unsigned short*)alloc((size_t)E * 2);
    unsigned short* edge_src = (unsigned short*)alloc((size_t)E * 2);
    float* Hs = (float*)alloc((size_t)N * DFEAT * 4);
    int* offs = (int*)alloc((size_t)(N + 1) * 4);
    int* tot = (int*)alloc((size_t)N * 4);
    float* dinv = (float*)alloc((size_t)N * 4);

    hist_kernel<<<nblk, 1024, 0, stream>>>(ei, E, Epb, N, packedHist, rank16);
    colscan_kernel<<<(N + 63) / 64, 64, 0, stream>>>(packedHist, dinv, tot, N, nblk);
    {
        int B = (N + 1023) / 1024;  // 10 for N=10000 (<= 24)
        scan_kernel<<<1, 1024, 0, stream>>>(tot, offs, N, B);
    }
    {
        int subPerBlk = 1024 / nblk;  // grid = 1024 blocks total
        if (subPerBlk < 1) subPerBlk = 1;
        fillscale_kernel<<<nblk * subPerBlk, 256, 0, stream>>>(
            ei, E, Epb, N, offs, packedHist, rank16, edge_src, H, dinv, Hs, nblk, subPerBlk);
    }
    agg_kernel<<<(N + 3) / 4, 256, 0, stream>>>(Hs, offs, edge_src, out, N);
    {
        int grid = 320;
        mmln_kernel<<<grid, 256, 0, stream>>>(W, bias, gamma, beta, out, N);
    }
}